// Round 19
// baseline (1656.156 us; speedup 1.0000x reference)
//
#include <hip/hip_runtime.h>

#define NN 200000
#define NPAD 200064            // 521 * 384, k_mlp tiles of 384 nodes
#define NTIL 521
#define NE 2000000
#define DD 128
#define EPSF 1e-5f

typedef short short4v __attribute__((ext_vector_type(4)));
typedef short short8v __attribute__((ext_vector_type(8)));
typedef float f32x4 __attribute__((ext_vector_type(4)));
typedef float f32x2 __attribute__((ext_vector_type(2)));
typedef unsigned long long u64;

__device__ __forceinline__ ushort f2bf(float f) {
  uint u = __float_as_uint(f);
  uint r = u + 0x7fff + ((u >> 16) & 1);
  return (ushort)(r >> 16);
}
__device__ __forceinline__ float bf2f(ushort u) { return __uint_as_float(((uint)u) << 16); }
__device__ __forceinline__ float bflo(uint v) { return __uint_as_float(v << 16); }
__device__ __forceinline__ float bfhi(uint v) { return __uint_as_float(v & 0xffff0000u); }
__device__ __forceinline__ uint packbf(float a, float b) {
  return (uint)f2bf(a) | ((uint)f2bf(b) << 16);
}

// ---------------- node init: h = bf16(x_emb1[x0] + x_emb2[x1]) ----------------
__global__ __launch_bounds__(256) void k_init(const int* __restrict__ x,
    const float* __restrict__ e1, const float* __restrict__ e2,
    uint* __restrict__ h) {
  int t = blockIdx.x * 256 + threadIdx.x;
  if (t >= NN * 64) return;
  int node = t >> 6, cp = (t & 63) << 1;
  int a = x[2 * node], b = x[2 * node + 1];
  float2 va = *(const float2*)(e1 + (size_t)a * DD + cp);
  float2 vb = *(const float2*)(e2 + (size_t)b * DD + cp);
  h[t] = packbf(va.x + vb.x, va.y + vb.y);
}

// ---- weight cast to FRAGMENT-TILED layout: wt[ct][kb][lane][8]
__global__ __launch_bounds__(256) void k_cvtw(const float* __restrict__ w,
    ushort* __restrict__ wt, int K, int Nc) {
  int t = blockIdx.x * 256 + threadIdx.x;
  if (t >= 5 * K * Nc) return;
  int per = K * Nc;
  int l = t / per, r0 = t % per;
  int j = r0 & 7, lane = (r0 >> 3) & 63, idx = r0 >> 9;
  int KB = K >> 5;
  int kb = idx % KB, ct = idx / KB;
  int lr = lane & 15, qq = lane >> 4;
  int n = ct * 16 + lr;
  int k = kb * 32 + qq * 4 + (j & 3) + ((j >> 2) << 4);
  wt[t] = f2bf(w[(size_t)l * per + (size_t)k * Nc + n]);
}

// ------- histogram: one u64 atomic per edge into XCD-sharded copies ----------
__global__ __launch_bounds__(256) void k_hist(const int* __restrict__ ei,
    const int* __restrict__ ea, u64* __restrict__ hist8) {
  int e = blockIdx.x * 256 + threadIdx.x;
  if (e >= NE) return;
  int d = ei[NE + e];
  int a0 = ea[2 * e];
  int a1 = ea[2 * e + 1];
  u64 v = (1ull << (a0 * 10)) | (1ull << (30 + a1 * 10));
  atomicAdd(&hist8[(size_t)(blockIdx.x & 7) * NN + d], v);
}

__global__ __launch_bounds__(256) void k_scan1(const u64* __restrict__ hist8,
    u64* __restrict__ histsum, int* __restrict__ off, int* __restrict__ bsum) {
  __shared__ int sh[256];
  int i = blockIdx.x * 256 + threadIdx.x;
  int v = 0;
  if (i < NN) {
    u64 s = 0;
#pragma unroll
    for (int cc = 0; cc < 8; ++cc) s += hist8[(size_t)cc * NN + i];
    histsum[i] = s;
    v = (int)((s & 1023) + ((s >> 10) & 1023) + ((s >> 20) & 1023));
  }
  sh[threadIdx.x] = v;
  __syncthreads();
  for (int d = 1; d < 256; d <<= 1) {
    int xv = 0;
    if (threadIdx.x >= d) xv = sh[threadIdx.x - d];
    __syncthreads();
    if (threadIdx.x >= d) sh[threadIdx.x] += xv;
    __syncthreads();
  }
  if (i < NN) off[i] = sh[threadIdx.x] - v;
  if (threadIdx.x == 255) bsum[blockIdx.x] = sh[255];
}

__global__ __launch_bounds__(1024) void k_scan2(const int* __restrict__ bsum,
    int* __restrict__ boff, int nb) {
  __shared__ int sh[1024];
  int t = threadIdx.x;
  int v = (t < nb) ? bsum[t] : 0;
  sh[t] = v;
  __syncthreads();
  for (int d = 1; d < 1024; d <<= 1) {
    int xv = 0;
    if (t >= d) xv = sh[t - d];
    __syncthreads();
    if (t >= d) sh[t] += xv;
    __syncthreads();
  }
  if (t < nb) boff[t] = sh[t] - v;
}

// scan3: final node offsets + per-shard segment cursors (from hist8 degrees)
__global__ __launch_bounds__(256) void k_scan3(int* __restrict__ off,
    const int* __restrict__ boff, const u64* __restrict__ hist8,
    int* __restrict__ cursor8) {
  int i = blockIdx.x * 256 + threadIdx.x;
  if (i < NN) {
    int o = off[i] + boff[i >> 8];
    off[i] = o;
    int run = o;
#pragma unroll
    for (int s = 0; s < 8; ++s) {
      cursor8[(size_t)s * NN + i] = run;
      u64 hs = hist8[(size_t)s * NN + i];
      run += (int)((hs & 1023) + ((hs >> 10) & 1023) + ((hs >> 20) & 1023));
    }
  }
  if (i == 0) off[NN] = NE;
}

// scatter with XCD-local shard cursors (same blockIdx&7 mapping as k_hist)
__global__ __launch_bounds__(256) void k_scatter(const int* __restrict__ ei,
    int* __restrict__ cursor8, int* __restrict__ csr_src) {
  int e = blockIdx.x * 256 + threadIdx.x;
  if (e >= NE) return;
  int d = ei[NE + e];
  int p = atomicAdd(&cursor8[(size_t)(blockIdx.x & 7) * NN + d], 1);
  csr_src[p] = ei[e];
}

// -------- aggregate: 2 nodes/wave, 32-lane epilogue, plane-split stores ------
__global__ __launch_bounds__(256) void k_agg(const uint* __restrict__ h,
    uint* __restrict__ agghi, uint* __restrict__ agglo,
    const int* __restrict__ off, const int* __restrict__ src,
    const u64* __restrict__ hist,
    const float* __restrict__ E1, const float* __restrict__ E2) {
  int lane = threadIdx.x & 63;
  int wid = threadIdx.x >> 6;
  int nb = blockIdx.x * 8 + wid * 2;
  int half = lane >> 5;
  int sub = (lane >> 4) & 1;
  int c = lane & 15;
  int node = nb + half;

  int o0 = off[nb], o1 = off[nb + 1], o2 = off[nb + 2];
  int deg0 = o1 - o0, deg1 = o2 - o1;
  int begh = half ? o1 : o0;
  int degh = half ? deg1 : deg0;
  int dmax = max(deg0, deg1);

  f32x2 acc[4];
#pragma unroll
  for (int j = 0; j < 4; ++j) acc[j] = (f32x2){0.f, 0.f};

#define ACCV(V)                                                           \
  {                                                                       \
    acc[0] += (f32x2){bflo(V.x), bfhi(V.x)};                              \
    acc[1] += (f32x2){bflo(V.y), bfhi(V.y)};                              \
    acc[2] += (f32x2){bflo(V.z), bfhi(V.z)};                              \
    acc[3] += (f32x2){bflo(V.w), bfhi(V.w)};                              \
  }

  for (int base = 0; base < dmax; base += 32) {
    int nremh = degh - base;
    nremh = nremh < 0 ? 0 : (nremh > 32 ? 32 : nremh);   // per-half count
    int li = lane & 31;
    int myidx = 0;
    if (li < nremh) myidx = src[begh + base + li];
    int r0 = deg0 - base; r0 = r0 < 0 ? 0 : (r0 > 32 ? 32 : r0);
    int r1 = deg1 - base; r1 = r1 < 0 ? 0 : (r1 > 32 ? 32 : r1);
    int niter = (max(r0, r1) + 1) >> 1;                  // wave-uniform
    for (int m = 0; m < niter; m += 4) {
#pragma unroll
      for (int u = 0; u < 4; ++u) {
        if (m + u < niter) {                             // uniform
          int sl = 2 * (m + u) + sub;
          int srcl = (half << 5) + max(min(sl, nremh - 1), 0);
          int s = __shfl(myidx, srcl);
          uint4 v = *(const uint4*)(h + (size_t)s * 64 + c * 4);
          if (sl < nremh) ACCV(v);
        }
      }
    }
  }
  // combine the 2 subs of each half
#pragma unroll
  for (int j = 0; j < 4; ++j) {
    acc[j][0] += __shfl_xor(acc[j][0], 16);
    acc[j][1] += __shfl_xor(acc[j][1], 16);
  }

  // epilogue on ALL lanes (both subs compute a[]; plane-split at store)
  uint4 sv = *(const uint4*)(h + (size_t)node * 64 + c * 4);
  ACCV(sv);   // self loop
  float a[8];
#pragma unroll
  for (int j = 0; j < 4; ++j) { a[2 * j] = acc[j][0]; a[2 * j + 1] = acc[j][1]; }
  u64 hv = hist[node];
  float cnt[7] = {
    (float)(int)(hv & 1023),
    (float)(int)((hv >> 10) & 1023),
    (float)(int)((hv >> 20) & 1023),
    1.f,
    (float)(int)((hv >> 30) & 1023) + 1.f,
    (float)(int)((hv >> 40) & 1023),
    (float)(int)((hv >> 50) & 1023)
  };
  const float* rows[7] = {E1, E1 + DD, E1 + 2 * DD, E1 + 4 * DD,
                          E2, E2 + DD, E2 + 2 * DD};
#pragma unroll
  for (int q = 0; q < 7; ++q) {
    f32x4 e0 = *(const f32x4*)(rows[q] + c * 8);
    f32x4 e1v = *(const f32x4*)(rows[q] + c * 8 + 4);
#pragma unroll
    for (int j = 0; j < 4; ++j) { a[j] += cnt[q] * e0[j]; a[4 + j] += cnt[q] * e1v[j]; }
  }
  // hi pack (needed by both planes)
  ushort hbuf[8];
#pragma unroll
  for (int j = 0; j < 8; ++j) hbuf[j] = f2bf(a[j]);
  uint2 v01, v23;
  if (sub == 0) {       // hi plane values
    v01.x = (uint)hbuf[0] | ((uint)hbuf[1] << 16);
    v01.y = (uint)hbuf[2] | ((uint)hbuf[3] << 16);
    v23.x = (uint)hbuf[4] | ((uint)hbuf[5] << 16);
    v23.y = (uint)hbuf[6] | ((uint)hbuf[7] << 16);
  } else {              // lo plane values
    v01.x = (uint)f2bf(a[0] - bf2f(hbuf[0])) | ((uint)f2bf(a[1] - bf2f(hbuf[1])) << 16);
    v01.y = (uint)f2bf(a[2] - bf2f(hbuf[2])) | ((uint)f2bf(a[3] - bf2f(hbuf[3])) << 16);
    v23.x = (uint)f2bf(a[4] - bf2f(hbuf[4])) | ((uint)f2bf(a[5] - bf2f(hbuf[5])) << 16);
    v23.y = (uint)f2bf(a[6] - bf2f(hbuf[6])) | ((uint)f2bf(a[7] - bf2f(hbuf[7])) << 16);
  }
  uint* dst = sub ? agglo : agghi;
  int wb = ((c >> 2) << 4) + ((c & 1) << 3) + (((c >> 1) & 1) << 1);
  *(uint2*)(dst + (size_t)node * 64 + wb) = v01;
  *(uint2*)(dst + (size_t)node * 64 + wb + 4) = v23;
#undef ACCV
}

// ------- fused MLP + BN-stats: weights in LDS, 768 thr (12 waves, 3/SIMD) ----
__global__ __launch_bounds__(768, 1) void k_mlp(
    const ushort* __restrict__ agghi, const ushort* __restrict__ agglo,
    const ushort* __restrict__ w1,    // fragment-tiled [16ct][4kb][64][8] bf16
    const float* __restrict__ b1,
    const ushort* __restrict__ w2,    // fragment-tiled [8ct][8kb][64][8] bf16
    const float* __restrict__ b2, uint* __restrict__ hnb,
    float* __restrict__ bnsums) {
  __shared__ uint4 smem4[8192];                // 128 KB: w1 (64K) | w2 (64K)
  __shared__ float sstat[256];                 // col sums | sumsq
  const ushort* sw1 = (const ushort*)smem4;
  const ushort* sw2 = (const ushort*)(smem4 + 4096);
  int t = threadIdx.x;
  int lane = t & 63;
  int wid = t >> 6;
  int nb = blockIdx.x * 384 + wid * 32;
  int lr = lane & 15, qq = lane >> 4;

  if (t < 256) sstat[t] = 0.f;

  // A fragments: single 16B loads (frag-swizzled layout); issued before staging
  short8v afh[2][4], afl[2][4];
#pragma unroll
  for (int g = 0; g < 2; ++g) {
    const ushort* ph = agghi + (size_t)(nb + g * 16 + lr) * 128 + qq * 8;
    const ushort* pl = agglo + (size_t)(nb + g * 16 + lr) * 128 + qq * 8;
#pragma unroll
    for (int kb = 0; kb < 4; ++kb) {
      afh[g][kb] = *(const short8v*)(ph + kb * 32);
      afl[g][kb] = *(const short8v*)(pl + kb * 32);
    }
  }

  // cooperative weight staging: 2 x 64KB, coalesced 16B per thread per iter
  {
    const uint4* g1 = (const uint4*)w1;
    const uint4* g2 = (const uint4*)w2;
    for (int i = t; i < 4096; i += 768) smem4[i] = g1[i];
    for (int i = t; i < 4096; i += 768) smem4[4096 + i] = g2[i];
  }
  __syncthreads();

  f32x4 acc2[2][8];
#pragma unroll
  for (int g = 0; g < 2; ++g)
#pragma unroll
    for (int ct = 0; ct < 8; ++ct) acc2[g][ct] = (f32x4){0.f, 0.f, 0.f, 0.f};

#pragma unroll
  for (int ph = 0; ph < 4; ++ph) {
    f32x4 acc1[2][4];
#pragma unroll
    for (int g = 0; g < 2; ++g)
#pragma unroll
      for (int ct = 0; ct < 4; ++ct) acc1[g][ct] = (f32x4){0.f, 0.f, 0.f, 0.f};
#pragma unroll
    for (int ct = 0; ct < 4; ++ct) {
      int gct = ph * 4 + ct;
#pragma unroll
      for (int kb = 0; kb < 4; ++kb) {
        short8v wf = *(const short8v*)(sw1 + ((gct * 4 + kb) * 64 + lane) * 8);
        acc1[0][ct] = __builtin_amdgcn_mfma_f32_16x16x32_bf16(wf, afh[0][kb], acc1[0][ct], 0, 0, 0);
        acc1[0][ct] = __builtin_amdgcn_mfma_f32_16x16x32_bf16(wf, afl[0][kb], acc1[0][ct], 0, 0, 0);
        acc1[1][ct] = __builtin_amdgcn_mfma_f32_16x16x32_bf16(wf, afh[1][kb], acc1[1][ct], 0, 0, 0);
        acc1[1][ct] = __builtin_amdgcn_mfma_f32_16x16x32_bf16(wf, afl[1][kb], acc1[1][ct], 0, 0, 0);
      }
    }
    short8v hfh[2][2], hfl[2][2];
#pragma unroll
    for (int i = 0; i < 2; ++i) {
      f32x4 ba = *(const f32x4*)(b1 + (ph * 4 + 2 * i) * 16 + qq * 4);
      f32x4 bb = *(const f32x4*)(b1 + (ph * 4 + 2 * i + 1) * 16 + qq * 4);
#pragma unroll
      for (int g = 0; g < 2; ++g) {
        short8v hh, hl;
#pragma unroll
        for (int r = 0; r < 4; ++r) {
          float va = fmaxf(acc1[g][2 * i][r] + ba[r], 0.f);
          float vb = fmaxf(acc1[g][2 * i + 1][r] + bb[r], 0.f);
          ushort ha = f2bf(va), hb = f2bf(vb);
          hh[r] = (short)ha; hh[4 + r] = (short)hb;
          hl[r] = (short)f2bf(va - bf2f(ha));
          hl[4 + r] = (short)f2bf(vb - bf2f(hb));
        }
        hfh[g][i] = hh; hfl[g][i] = hl;
      }
    }
#pragma unroll
    for (int ct = 0; ct < 8; ++ct) {
#pragma unroll
      for (int i = 0; i < 2; ++i) {
        int kb2 = ph * 2 + i;
        short8v wf = *(const short8v*)(sw2 + ((ct * 8 + kb2) * 64 + lane) * 8);
        acc2[0][ct] = __builtin_amdgcn_mfma_f32_16x16x32_bf16(wf, hfh[0][i], acc2[0][ct], 0, 0, 0);
        acc2[0][ct] = __builtin_amdgcn_mfma_f32_16x16x32_bf16(wf, hfl[0][i], acc2[0][ct], 0, 0, 0);
        acc2[1][ct] = __builtin_amdgcn_mfma_f32_16x16x32_bf16(wf, hfh[1][i], acc2[1][ct], 0, 0, 0);
        acc2[1][ct] = __builtin_amdgcn_mfma_f32_16x16x32_bf16(wf, hfl[1][i], acc2[1][ct], 0, 0, 0);
      }
    }
  }

  // epilogue: bias, masked BN partial stats (exact fp32), bf16 hn stores
  int n0 = nb + lr, n1 = nb + 16 + lr;
  float m0 = (n0 < NN) ? 1.f : 0.f;
  float m1 = (n1 < NN) ? 1.f : 0.f;
#pragma unroll
  for (int ct = 0; ct < 8; ++ct) {
    f32x4 bb = *(const f32x4*)(b2 + ct * 16 + qq * 4);
    f32x4 o0, o1;
#pragma unroll
    for (int r = 0; r < 4; ++r) {
      o0[r] = acc2[0][ct][r] + bb[r];
      o1[r] = acc2[1][ct][r] + bb[r];
    }
#pragma unroll
    for (int r = 0; r < 4; ++r) {
      float s = m0 * o0[r] + m1 * o1[r];
      float q = m0 * o0[r] * o0[r] + m1 * o1[r] * o1[r];
      s += __shfl_xor(s, 1); q += __shfl_xor(q, 1);
      s += __shfl_xor(s, 2); q += __shfl_xor(q, 2);
      s += __shfl_xor(s, 4); q += __shfl_xor(q, 4);
      s += __shfl_xor(s, 8); q += __shfl_xor(q, 8);
      if (lr == 0) {
        int col = ct * 16 + qq * 4 + r;
        atomicAdd(&sstat[col], s);
        atomicAdd(&sstat[128 + col], q);
      }
    }
    if (n0 < NN) {
      uint2 wv;
      wv.x = packbf(o0[0], o0[1]);
      wv.y = packbf(o0[2], o0[3]);
      *(uint2*)(hnb + (size_t)n0 * 64 + ct * 8 + qq * 2) = wv;
    }
    if (n1 < NN) {
      uint2 wv;
      wv.x = packbf(o1[0], o1[1]);
      wv.y = packbf(o1[2], o1[3]);
      *(uint2*)(hnb + (size_t)n1 * 64 + ct * 8 + qq * 2) = wv;
    }
  }
  __syncthreads();
  if (t < 256) atomicAdd(&bnsums[t], sstat[t]);
}

// -------- BN apply: bf16 hn -> bf16 h (+relu) or fp32 out (final) -----------
__global__ __launch_bounds__(256) void k_bnapply(const uint* __restrict__ hnb,
    const float* __restrict__ sums, const float* __restrict__ gamma,
    const float* __restrict__ beta, uint* __restrict__ hout,
    float* __restrict__ fout, int final_layer) {
  int t = blockIdx.x * 256 + threadIdx.x;
  if (t >= NN * 64) return;
  int node = t >> 6, cp = (t & 63) << 1;
  uint v = hnb[t];
  float r[2] = {bflo(v), bfhi(v)};
#pragma unroll
  for (int j = 0; j < 2; ++j) {
    int col = cp + j;
    float mean = sums[col] * (1.f / NN);
    float var = sums[128 + col] * (1.f / NN) - mean * mean;
    float scale = gamma[col] * rsqrtf(var + EPSF);
    r[j] = (r[j] - mean) * scale + beta[col];
  }
  if (final_layer) {
    *(float2*)(fout + (size_t)node * DD + cp) = make_float2(r[0], r[1]);
  } else {
    hout[t] = packbf(fmaxf(r[0], 0.f), fmaxf(r[1], 0.f));
  }
}

extern "C" void kernel_launch(void* const* d_in, const int* in_sizes, int n_in,
                              void* d_out, int out_size, void* d_ws, size_t ws_size,
                              hipStream_t stream) {
  const int* x    = (const int*)d_in[0];
  const int* ei   = (const int*)d_in[1];
  const int* ea   = (const int*)d_in[2];
  const float* xe1 = (const float*)d_in[3];
  const float* xe2 = (const float*)d_in[4];
  const float* ee1 = (const float*)d_in[5];   // [5][6][128]
  const float* ee2 = (const float*)d_in[6];   // [5][3][128]
  const float* w1  = (const float*)d_in[7];   // [5][128][256]
  const float* b1  = (const float*)d_in[8];   // [5][256]
  const float* w2  = (const float*)d_in[9];   // [5][256][128]
  const float* b2  = (const float*)d_in[10];  // [5][128]
  const float* gam = (const float*)d_in[11];
  const float* bet = (const float*)d_in[12];
  float* out = (float*)d_out;

  char* p = (char*)d_ws;
  auto alloc = [&](size_t bytes) {
    char* r = p;
    p += (bytes + 255) & ~(size_t)255;
    return r;
  };
  uint* h      = (uint*)alloc((size_t)NN * 64 * 4);    // bf16x2 packed, linear
  uint* agghi  = (uint*)alloc((size_t)NPAD * 64 * 4);  // bf16x2, frag-swizzled
  uint* agglo  = (uint*)alloc((size_t)NPAD * 64 * 4);
  uint* hnb    = (uint*)alloc((size_t)NPAD * 64 * 4);  // bf16x2 packed hn
  ushort* w1t  = (ushort*)alloc((size_t)5 * 128 * 256 * 2);
  ushort* w2t  = (ushort*)alloc((size_t)5 * 256 * 128 * 2);
  u64* hist8   = (u64*)alloc((size_t)8 * NN * 8);
  u64* histsum = (u64*)alloc((size_t)NN * 8);
  int* csroff  = (int*)alloc((size_t)(NN + 1) * 4);
  int* cursor8 = (int*)alloc((size_t)8 * NN * 4);
  int* csrsrc  = (int*)alloc((size_t)NE * 4);
  int* bsum    = (int*)alloc(4096);
  int* boff    = (int*)alloc(4096);
  float* bnsums = (float*)alloc(5 * 1024);             // 256 floats per layer

  const int nscan = (NN + 255) / 256;   // 782

  hipMemsetAsync(hist8, 0, (size_t)8 * NN * 8, stream);
  hipMemsetAsync(bnsums, 0, 5 * 1024, stream);

  k_cvtw<<<(5 * 128 * 256 + 255) / 256, 256, 0, stream>>>(w1, w1t, 128, 256);
  k_cvtw<<<(5 * 256 * 128 + 255) / 256, 256, 0, stream>>>(w2, w2t, 256, 128);
  k_init<<<(NN * 64 + 255) / 256, 256, 0, stream>>>(x, xe1, xe2, h);
  k_hist<<<(NE + 255) / 256, 256, 0, stream>>>(ei, ea, hist8);
  k_scan1<<<nscan, 256, 0, stream>>>(hist8, histsum, csroff, bsum);
  k_scan2<<<1, 1024, 0, stream>>>(bsum, boff, nscan);
  k_scan3<<<nscan, 256, 0, stream>>>(csroff, boff, hist8, cursor8);
  k_scatter<<<(NE + 255) / 256, 256, 0, stream>>>(ei, cursor8, csrsrc);

  for (int l = 0; l < 5; ++l) {
    k_agg<<<NN / 8, 256, 0, stream>>>(h, agghi, agglo, csroff, csrsrc, histsum,
                                      ee1 + (size_t)l * 6 * DD,
                                      ee2 + (size_t)l * 3 * DD);
    k_mlp<<<NTIL, 768, 0, stream>>>((const ushort*)agghi, (const ushort*)agglo,
                                    w1t + (size_t)l * 128 * 256,
                                    b1 + (size_t)l * 256,
                                    w2t + (size_t)l * 256 * 128,
                                    b2 + (size_t)l * DD, hnb,
                                    bnsums + (size_t)l * 256);
    k_bnapply<<<(NN * 64 + 255) / 256, 256, 0, stream>>>(
        hnb, bnsums + (size_t)l * 256, gam + (size_t)l * DD, bet + (size_t)l * DD,
        h, out, l == 4 ? 1 : 0);
  }
}

// Round 20
// 1458.964 us; speedup vs baseline: 1.1352x; 1.1352x over previous
//
#include <hip/hip_runtime.h>

#define NN 200000
#define NPAD 200192            // 782 * 256, k_mlp tiles of 256 nodes
#define NE 2000000
#define DD 128
#define EPSF 1e-5f

typedef short short4v __attribute__((ext_vector_type(4)));
typedef short short8v __attribute__((ext_vector_type(8)));
typedef float f32x4 __attribute__((ext_vector_type(4)));
typedef float f32x2 __attribute__((ext_vector_type(2)));
typedef unsigned long long u64;

__device__ __forceinline__ ushort f2bf(float f) {
  uint u = __float_as_uint(f);
  uint r = u + 0x7fff + ((u >> 16) & 1);
  return (ushort)(r >> 16);
}
__device__ __forceinline__ float bf2f(ushort u) { return __uint_as_float(((uint)u) << 16); }
__device__ __forceinline__ float bflo(uint v) { return __uint_as_float(v << 16); }
__device__ __forceinline__ float bfhi(uint v) { return __uint_as_float(v & 0xffff0000u); }
__device__ __forceinline__ uint packbf(float a, float b) {
  return (uint)f2bf(a) | ((uint)f2bf(b) << 16);
}

// ---------------- node init: h = bf16(x_emb1[x0] + x_emb2[x1]) ----------------
__global__ __launch_bounds__(256) void k_init(const int* __restrict__ x,
    const float* __restrict__ e1, const float* __restrict__ e2,
    uint* __restrict__ h) {
  int t = blockIdx.x * 256 + threadIdx.x;
  if (t >= NN * 64) return;
  int node = t >> 6, cp = (t & 63) << 1;
  int a = x[2 * node], b = x[2 * node + 1];
  float2 va = *(const float2*)(e1 + (size_t)a * DD + cp);
  float2 vb = *(const float2*)(e2 + (size_t)b * DD + cp);
  h[t] = packbf(va.x + vb.x, va.y + vb.y);
}

// ---- weight cast to FRAGMENT-TILED layout: wt[ct][kb][lane][8]
__global__ __launch_bounds__(256) void k_cvtw(const float* __restrict__ w,
    ushort* __restrict__ wt, int K, int Nc) {
  int t = blockIdx.x * 256 + threadIdx.x;
  if (t >= 5 * K * Nc) return;
  int per = K * Nc;
  int l = t / per, r0 = t % per;
  int j = r0 & 7, lane = (r0 >> 3) & 63, idx = r0 >> 9;
  int KB = K >> 5;
  int kb = idx % KB, ct = idx / KB;
  int lr = lane & 15, qq = lane >> 4;
  int n = ct * 16 + lr;
  int k = kb * 32 + qq * 4 + (j & 3) + ((j >> 2) << 4);
  wt[t] = f2bf(w[(size_t)l * per + (size_t)k * Nc + n]);
}

// ------- histogram: one u64 atomic per edge into XCD-sharded copies ----------
__global__ __launch_bounds__(256) void k_hist(const int* __restrict__ ei,
    const int* __restrict__ ea, u64* __restrict__ hist8) {
  int e = blockIdx.x * 256 + threadIdx.x;
  if (e >= NE) return;
  int d = ei[NE + e];
  int a0 = ea[2 * e];
  int a1 = ea[2 * e + 1];
  u64 v = (1ull << (a0 * 10)) | (1ull << (30 + a1 * 10));
  atomicAdd(&hist8[(size_t)(blockIdx.x & 7) * NN + d], v);
}

__global__ __launch_bounds__(256) void k_scan1(const u64* __restrict__ hist8,
    u64* __restrict__ histsum, int* __restrict__ off, int* __restrict__ bsum) {
  __shared__ int sh[256];
  int i = blockIdx.x * 256 + threadIdx.x;
  int v = 0;
  if (i < NN) {
    u64 s = 0;
#pragma unroll
    for (int cc = 0; cc < 8; ++cc) s += hist8[(size_t)cc * NN + i];
    histsum[i] = s;
    v = (int)((s & 1023) + ((s >> 10) & 1023) + ((s >> 20) & 1023));
  }
  sh[threadIdx.x] = v;
  __syncthreads();
  for (int d = 1; d < 256; d <<= 1) {
    int xv = 0;
    if (threadIdx.x >= d) xv = sh[threadIdx.x - d];
    __syncthreads();
    if (threadIdx.x >= d) sh[threadIdx.x] += xv;
    __syncthreads();
  }
  if (i < NN) off[i] = sh[threadIdx.x] - v;
  if (threadIdx.x == 255) bsum[blockIdx.x] = sh[255];
}

__global__ __launch_bounds__(1024) void k_scan2(const int* __restrict__ bsum,
    int* __restrict__ boff, int nb) {
  __shared__ int sh[1024];
  int t = threadIdx.x;
  int v = (t < nb) ? bsum[t] : 0;
  sh[t] = v;
  __syncthreads();
  for (int d = 1; d < 1024; d <<= 1) {
    int xv = 0;
    if (t >= d) xv = sh[t - d];
    __syncthreads();
    if (t >= d) sh[t] += xv;
    __syncthreads();
  }
  if (t < nb) boff[t] = sh[t] - v;
}

// scan3: final node offsets + per-shard segment cursors (from hist8 degrees)
__global__ __launch_bounds__(256) void k_scan3(int* __restrict__ off,
    const int* __restrict__ boff, const u64* __restrict__ hist8,
    int* __restrict__ cursor8) {
  int i = blockIdx.x * 256 + threadIdx.x;
  if (i < NN) {
    int o = off[i] + boff[i >> 8];
    off[i] = o;
    int run = o;
#pragma unroll
    for (int s = 0; s < 8; ++s) {
      cursor8[(size_t)s * NN + i] = run;
      u64 hs = hist8[(size_t)s * NN + i];
      run += (int)((hs & 1023) + ((hs >> 10) & 1023) + ((hs >> 20) & 1023));
    }
  }
  if (i == 0) off[NN] = NE;
}

// scatter with XCD-local shard cursors (same blockIdx&7 mapping as k_hist)
__global__ __launch_bounds__(256) void k_scatter(const int* __restrict__ ei,
    int* __restrict__ cursor8, int* __restrict__ csr_src) {
  int e = blockIdx.x * 256 + threadIdx.x;
  if (e >= NE) return;
  int d = ei[NE + e];
  int p = atomicAdd(&cursor8[(size_t)(blockIdx.x & 7) * NN + d], 1);
  csr_src[p] = ei[e];
}

// -------- aggregate: 2 nodes/wave, 32-lane epilogue, plane-split stores ------
__global__ __launch_bounds__(256) void k_agg(const uint* __restrict__ h,
    uint* __restrict__ agghi, uint* __restrict__ agglo,
    const int* __restrict__ off, const int* __restrict__ src,
    const u64* __restrict__ hist,
    const float* __restrict__ E1, const float* __restrict__ E2) {
  int lane = threadIdx.x & 63;
  int wid = threadIdx.x >> 6;
  int nb = blockIdx.x * 8 + wid * 2;
  int half = lane >> 5;
  int sub = (lane >> 4) & 1;
  int c = lane & 15;
  int node = nb + half;

  int o0 = off[nb], o1 = off[nb + 1], o2 = off[nb + 2];
  int deg0 = o1 - o0, deg1 = o2 - o1;
  int begh = half ? o1 : o0;
  int degh = half ? deg1 : deg0;
  int dmax = max(deg0, deg1);

  f32x2 acc[4];
#pragma unroll
  for (int j = 0; j < 4; ++j) acc[j] = (f32x2){0.f, 0.f};

#define ACCV(V)                                                           \
  {                                                                       \
    acc[0] += (f32x2){bflo(V.x), bfhi(V.x)};                              \
    acc[1] += (f32x2){bflo(V.y), bfhi(V.y)};                              \
    acc[2] += (f32x2){bflo(V.z), bfhi(V.z)};                              \
    acc[3] += (f32x2){bflo(V.w), bfhi(V.w)};                              \
  }

  for (int base = 0; base < dmax; base += 32) {
    int nremh = degh - base;
    nremh = nremh < 0 ? 0 : (nremh > 32 ? 32 : nremh);   // per-half count
    int li = lane & 31;
    int myidx = 0;
    if (li < nremh) myidx = src[begh + base + li];
    int r0 = deg0 - base; r0 = r0 < 0 ? 0 : (r0 > 32 ? 32 : r0);
    int r1 = deg1 - base; r1 = r1 < 0 ? 0 : (r1 > 32 ? 32 : r1);
    int niter = (max(r0, r1) + 1) >> 1;                  // wave-uniform
    for (int m = 0; m < niter; m += 4) {
#pragma unroll
      for (int u = 0; u < 4; ++u) {
        if (m + u < niter) {                             // uniform
          int sl = 2 * (m + u) + sub;
          int srcl = (half << 5) + max(min(sl, nremh - 1), 0);
          int s = __shfl(myidx, srcl);
          uint4 v = *(const uint4*)(h + (size_t)s * 64 + c * 4);
          if (sl < nremh) ACCV(v);
        }
      }
    }
  }
  // combine the 2 subs of each half
#pragma unroll
  for (int j = 0; j < 4; ++j) {
    acc[j][0] += __shfl_xor(acc[j][0], 16);
    acc[j][1] += __shfl_xor(acc[j][1], 16);
  }

  // epilogue on ALL lanes (both subs compute a[]; plane-split at store)
  uint4 sv = *(const uint4*)(h + (size_t)node * 64 + c * 4);
  ACCV(sv);   // self loop
  float a[8];
#pragma unroll
  for (int j = 0; j < 4; ++j) { a[2 * j] = acc[j][0]; a[2 * j + 1] = acc[j][1]; }
  u64 hv = hist[node];
  float cnt[7] = {
    (float)(int)(hv & 1023),
    (float)(int)((hv >> 10) & 1023),
    (float)(int)((hv >> 20) & 1023),
    1.f,
    (float)(int)((hv >> 30) & 1023) + 1.f,
    (float)(int)((hv >> 40) & 1023),
    (float)(int)((hv >> 50) & 1023)
  };
  const float* rows[7] = {E1, E1 + DD, E1 + 2 * DD, E1 + 4 * DD,
                          E2, E2 + DD, E2 + 2 * DD};
#pragma unroll
  for (int q = 0; q < 7; ++q) {
    f32x4 e0 = *(const f32x4*)(rows[q] + c * 8);
    f32x4 e1v = *(const f32x4*)(rows[q] + c * 8 + 4);
#pragma unroll
    for (int j = 0; j < 4; ++j) { a[j] += cnt[q] * e0[j]; a[4 + j] += cnt[q] * e1v[j]; }
  }
  // hi pack (needed by both planes)
  ushort hbuf[8];
#pragma unroll
  for (int j = 0; j < 8; ++j) hbuf[j] = f2bf(a[j]);
  uint2 v01, v23;
  if (sub == 0) {       // hi plane values
    v01.x = (uint)hbuf[0] | ((uint)hbuf[1] << 16);
    v01.y = (uint)hbuf[2] | ((uint)hbuf[3] << 16);
    v23.x = (uint)hbuf[4] | ((uint)hbuf[5] << 16);
    v23.y = (uint)hbuf[6] | ((uint)hbuf[7] << 16);
  } else {              // lo plane values
    v01.x = (uint)f2bf(a[0] - bf2f(hbuf[0])) | ((uint)f2bf(a[1] - bf2f(hbuf[1])) << 16);
    v01.y = (uint)f2bf(a[2] - bf2f(hbuf[2])) | ((uint)f2bf(a[3] - bf2f(hbuf[3])) << 16);
    v23.x = (uint)f2bf(a[4] - bf2f(hbuf[4])) | ((uint)f2bf(a[5] - bf2f(hbuf[5])) << 16);
    v23.y = (uint)f2bf(a[6] - bf2f(hbuf[6])) | ((uint)f2bf(a[7] - bf2f(hbuf[7])) << 16);
  }
  uint* dst = sub ? agglo : agghi;
  int wb = ((c >> 2) << 4) + ((c & 1) << 3) + (((c >> 1) & 1) << 1);
  *(uint2*)(dst + (size_t)node * 64 + wb) = v01;
  *(uint2*)(dst + (size_t)node * 64 + wb + 4) = v23;
#undef ACCV
}

// ------- fused MLP + BN-stats: both weights in LDS, 512 thr (r18-proven) ----
__global__ __launch_bounds__(512, 1) void k_mlp(
    const ushort* __restrict__ agghi, const ushort* __restrict__ agglo,
    const ushort* __restrict__ w1,    // fragment-tiled [16ct][4kb][64][8] bf16
    const float* __restrict__ b1,
    const ushort* __restrict__ w2,    // fragment-tiled [8ct][8kb][64][8] bf16
    const float* __restrict__ b2, uint* __restrict__ hnb,
    float* __restrict__ bnsums) {
  __shared__ uint4 smem4[8192];                // 128 KB: w1 (64K) | w2 (64K)
  __shared__ float sstat[256];                 // col sums | sumsq
  const ushort* sw1 = (const ushort*)smem4;
  const ushort* sw2 = (const ushort*)(smem4 + 4096);
  int t = threadIdx.x;
  int lane = t & 63;
  int wid = t >> 6;
  int nb = blockIdx.x * 256 + wid * 32;
  int lr = lane & 15, qq = lane >> 4;

  if (t < 256) sstat[t] = 0.f;

  // A fragments: single 16B loads (frag-swizzled layout); issued before staging
  short8v afh[2][4], afl[2][4];
#pragma unroll
  for (int g = 0; g < 2; ++g) {
    const ushort* ph = agghi + (size_t)(nb + g * 16 + lr) * 128 + qq * 8;
    const ushort* pl = agglo + (size_t)(nb + g * 16 + lr) * 128 + qq * 8;
#pragma unroll
    for (int kb = 0; kb < 4; ++kb) {
      afh[g][kb] = *(const short8v*)(ph + kb * 32);
      afl[g][kb] = *(const short8v*)(pl + kb * 32);
    }
  }

  // cooperative weight staging: 2 x 64KB, coalesced 16B per thread per iter
  {
    const uint4* g1 = (const uint4*)w1;
    const uint4* g2 = (const uint4*)w2;
#pragma unroll
    for (int i = 0; i < 8; ++i) smem4[i * 512 + t] = g1[i * 512 + t];
#pragma unroll
    for (int i = 0; i < 8; ++i) smem4[4096 + i * 512 + t] = g2[i * 512 + t];
  }
  __syncthreads();

  f32x4 acc2[2][8];
#pragma unroll
  for (int g = 0; g < 2; ++g)
#pragma unroll
    for (int ct = 0; ct < 8; ++ct) acc2[g][ct] = (f32x4){0.f, 0.f, 0.f, 0.f};

#pragma unroll
  for (int ph = 0; ph < 4; ++ph) {
    f32x4 acc1[2][4];
#pragma unroll
    for (int g = 0; g < 2; ++g)
#pragma unroll
      for (int ct = 0; ct < 4; ++ct) acc1[g][ct] = (f32x4){0.f, 0.f, 0.f, 0.f};
#pragma unroll
    for (int ct = 0; ct < 4; ++ct) {
      int gct = ph * 4 + ct;
#pragma unroll
      for (int kb = 0; kb < 4; ++kb) {
        short8v wf = *(const short8v*)(sw1 + ((gct * 4 + kb) * 64 + lane) * 8);
        acc1[0][ct] = __builtin_amdgcn_mfma_f32_16x16x32_bf16(wf, afh[0][kb], acc1[0][ct], 0, 0, 0);
        acc1[0][ct] = __builtin_amdgcn_mfma_f32_16x16x32_bf16(wf, afl[0][kb], acc1[0][ct], 0, 0, 0);
        acc1[1][ct] = __builtin_amdgcn_mfma_f32_16x16x32_bf16(wf, afh[1][kb], acc1[1][ct], 0, 0, 0);
        acc1[1][ct] = __builtin_amdgcn_mfma_f32_16x16x32_bf16(wf, afl[1][kb], acc1[1][ct], 0, 0, 0);
      }
    }
    short8v hfh[2][2], hfl[2][2];
#pragma unroll
    for (int i = 0; i < 2; ++i) {
      f32x4 ba = *(const f32x4*)(b1 + (ph * 4 + 2 * i) * 16 + qq * 4);
      f32x4 bb = *(const f32x4*)(b1 + (ph * 4 + 2 * i + 1) * 16 + qq * 4);
#pragma unroll
      for (int g = 0; g < 2; ++g) {
        short8v hh, hl;
#pragma unroll
        for (int r = 0; r < 4; ++r) {
          float va = fmaxf(acc1[g][2 * i][r] + ba[r], 0.f);
          float vb = fmaxf(acc1[g][2 * i + 1][r] + bb[r], 0.f);
          ushort ha = f2bf(va), hb = f2bf(vb);
          hh[r] = (short)ha; hh[4 + r] = (short)hb;
          hl[r] = (short)f2bf(va - bf2f(ha));
          hl[4 + r] = (short)f2bf(vb - bf2f(hb));
        }
        hfh[g][i] = hh; hfl[g][i] = hl;
      }
    }
#pragma unroll
    for (int ct = 0; ct < 8; ++ct) {
#pragma unroll
      for (int i = 0; i < 2; ++i) {
        int kb2 = ph * 2 + i;
        short8v wf = *(const short8v*)(sw2 + ((ct * 8 + kb2) * 64 + lane) * 8);
        acc2[0][ct] = __builtin_amdgcn_mfma_f32_16x16x32_bf16(wf, hfh[0][i], acc2[0][ct], 0, 0, 0);
        acc2[0][ct] = __builtin_amdgcn_mfma_f32_16x16x32_bf16(wf, hfl[0][i], acc2[0][ct], 0, 0, 0);
        acc2[1][ct] = __builtin_amdgcn_mfma_f32_16x16x32_bf16(wf, hfh[1][i], acc2[1][ct], 0, 0, 0);
        acc2[1][ct] = __builtin_amdgcn_mfma_f32_16x16x32_bf16(wf, hfl[1][i], acc2[1][ct], 0, 0, 0);
      }
    }
  }

  // epilogue: bias, masked BN partial stats (exact fp32), bf16 hn stores
  int n0 = nb + lr, n1 = nb + 16 + lr;
  float m0 = (n0 < NN) ? 1.f : 0.f;
  float m1 = (n1 < NN) ? 1.f : 0.f;
#pragma unroll
  for (int ct = 0; ct < 8; ++ct) {
    f32x4 bb = *(const f32x4*)(b2 + ct * 16 + qq * 4);
    f32x4 o0, o1;
#pragma unroll
    for (int r = 0; r < 4; ++r) {
      o0[r] = acc2[0][ct][r] + bb[r];
      o1[r] = acc2[1][ct][r] + bb[r];
    }
#pragma unroll
    for (int r = 0; r < 4; ++r) {
      float s = m0 * o0[r] + m1 * o1[r];
      float q = m0 * o0[r] * o0[r] + m1 * o1[r] * o1[r];
      s += __shfl_xor(s, 1); q += __shfl_xor(q, 1);
      s += __shfl_xor(s, 2); q += __shfl_xor(q, 2);
      s += __shfl_xor(s, 4); q += __shfl_xor(q, 4);
      s += __shfl_xor(s, 8); q += __shfl_xor(q, 8);
      if (lr == 0) {
        int col = ct * 16 + qq * 4 + r;
        atomicAdd(&sstat[col], s);
        atomicAdd(&sstat[128 + col], q);
      }
    }
    if (n0 < NN) {
      uint2 wv;
      wv.x = packbf(o0[0], o0[1]);
      wv.y = packbf(o0[2], o0[3]);
      *(uint2*)(hnb + (size_t)n0 * 64 + ct * 8 + qq * 2) = wv;
    }
    if (n1 < NN) {
      uint2 wv;
      wv.x = packbf(o1[0], o1[1]);
      wv.y = packbf(o1[2], o1[3]);
      *(uint2*)(hnb + (size_t)n1 * 64 + ct * 8 + qq * 2) = wv;
    }
  }
  __syncthreads();
  if (t < 256) atomicAdd(&bnsums[t], sstat[t]);
}

// -------- BN apply: bf16 hn -> bf16 h (+relu) or fp32 out (final) -----------
__global__ __launch_bounds__(256) void k_bnapply(const uint* __restrict__ hnb,
    const float* __restrict__ sums, const float* __restrict__ gamma,
    const float* __restrict__ beta, uint* __restrict__ hout,
    float* __restrict__ fout, int final_layer) {
  int t = blockIdx.x * 256 + threadIdx.x;
  if (t >= NN * 64) return;
  int node = t >> 6, cp = (t & 63) << 1;
  uint v = hnb[t];
  float r[2] = {bflo(v), bfhi(v)};
#pragma unroll
  for (int j = 0; j < 2; ++j) {
    int col = cp + j;
    float mean = sums[col] * (1.f / NN);
    float var = sums[128 + col] * (1.f / NN) - mean * mean;
    float scale = gamma[col] * rsqrtf(var + EPSF);
    r[j] = (r[j] - mean) * scale + beta[col];
  }
  if (final_layer) {
    *(float2*)(fout + (size_t)node * DD + cp) = make_float2(r[0], r[1]);
  } else {
    hout[t] = packbf(fmaxf(r[0], 0.f), fmaxf(r[1], 0.f));
  }
}

extern "C" void kernel_launch(void* const* d_in, const int* in_sizes, int n_in,
                              void* d_out, int out_size, void* d_ws, size_t ws_size,
                              hipStream_t stream) {
  const int* x    = (const int*)d_in[0];
  const int* ei   = (const int*)d_in[1];
  const int* ea   = (const int*)d_in[2];
  const float* xe1 = (const float*)d_in[3];
  const float* xe2 = (const float*)d_in[4];
  const float* ee1 = (const float*)d_in[5];   // [5][6][128]
  const float* ee2 = (const float*)d_in[6];   // [5][3][128]
  const float* w1  = (const float*)d_in[7];   // [5][128][256]
  const float* b1  = (const float*)d_in[8];   // [5][256]
  const float* w2  = (const float*)d_in[9];   // [5][256][128]
  const float* b2  = (const float*)d_in[10];  // [5][128]
  const float* gam = (const float*)d_in[11];
  const float* bet = (const float*)d_in[12];
  float* out = (float*)d_out;

  char* p = (char*)d_ws;
  auto alloc = [&](size_t bytes) {
    char* r = p;
    p += (bytes + 255) & ~(size_t)255;
    return r;
  };
  uint* h      = (uint*)alloc((size_t)NN * 64 * 4);    // bf16x2 packed, linear
  uint* agghi  = (uint*)alloc((size_t)NPAD * 64 * 4);  // bf16x2, frag-swizzled
  uint* agglo  = (uint*)alloc((size_t)NPAD * 64 * 4);
  uint* hnb    = (uint*)alloc((size_t)NPAD * 64 * 4);  // bf16x2 packed hn
  ushort* w1t  = (ushort*)alloc((size_t)5 * 128 * 256 * 2);
  ushort* w2t  = (ushort*)alloc((size_t)5 * 256 * 128 * 2);
  u64* hist8   = (u64*)alloc((size_t)8 * NN * 8);
  u64* histsum = (u64*)alloc((size_t)NN * 8);
  int* csroff  = (int*)alloc((size_t)(NN + 1) * 4);
  int* cursor8 = (int*)alloc((size_t)8 * NN * 4);
  int* csrsrc  = (int*)alloc((size_t)NE * 4);
  int* bsum    = (int*)alloc(4096);
  int* boff    = (int*)alloc(4096);
  float* bnsums = (float*)alloc(5 * 1024);             // 256 floats per layer

  const int nscan = (NN + 255) / 256;   // 782

  hipMemsetAsync(hist8, 0, (size_t)8 * NN * 8, stream);
  hipMemsetAsync(bnsums, 0, 5 * 1024, stream);

  k_cvtw<<<(5 * 128 * 256 + 255) / 256, 256, 0, stream>>>(w1, w1t, 128, 256);
  k_cvtw<<<(5 * 256 * 128 + 255) / 256, 256, 0, stream>>>(w2, w2t, 256, 128);
  k_init<<<(NN * 64 + 255) / 256, 256, 0, stream>>>(x, xe1, xe2, h);
  k_hist<<<(NE + 255) / 256, 256, 0, stream>>>(ei, ea, hist8);
  k_scan1<<<nscan, 256, 0, stream>>>(hist8, histsum, csroff, bsum);
  k_scan2<<<1, 1024, 0, stream>>>(bsum, boff, nscan);
  k_scan3<<<nscan, 256, 0, stream>>>(csroff, boff, hist8, cursor8);
  k_scatter<<<(NE + 255) / 256, 256, 0, stream>>>(ei, cursor8, csrsrc);

  for (int l = 0; l < 5; ++l) {
    k_agg<<<NN / 8, 256, 0, stream>>>(h, agghi, agglo, csroff, csrsrc, histsum,
                                      ee1 + (size_t)l * 6 * DD,
                                      ee2 + (size_t)l * 3 * DD);
    k_mlp<<<NPAD / 256, 512, 0, stream>>>((const ushort*)agghi, (const ushort*)agglo,
                                          w1t + (size_t)l * 128 * 256,
                                          b1 + (size_t)l * 256,
                                          w2t + (size_t)l * 256 * 128,
                                          b2 + (size_t)l * DD, hnb,
                                          bnsums + (size_t)l * 256);
    k_bnapply<<<(NN * 64 + 255) / 256, 256, 0, stream>>>(
        hnb, bnsums + (size_t)l * 256, gam + (size_t)l * DD, bet + (size_t)l * DD,
        h, out, l == 4 ? 1 : 0);
  }
}